// Round 1
// baseline (138.542 us; speedup 1.0000x reference)
//
#include <hip/hip_runtime.h>

// Problem: B=64 batches, N=M=1024 points, 3-D.
// loss1 = flag1 * (sym*chamfer(p1,t) + (1-sym)*l2(p1,t)), per batch, mean over points
// loss2 = same with p2/flag2. Output: [mean(loss1+loss2), mean(loss1), mean(loss2)].
// chamfer per point slot n: 0.5*(min_m d(a_n,t_m) + min_n' d(a_n',t_n))  (N==M slot-aligned)

#define BATCH 64
#define NPTS 1024

__global__ void zero_out_kernel(float* out) {
    if (threadIdx.x < 3) out[threadIdx.x] = 0.0f;
}

__global__ __launch_bounds__(256) void chamfer_loss_kernel(
    const float* __restrict__ p1g, const float* __restrict__ p2g,
    const float* __restrict__ tgg, const float* __restrict__ flag1,
    const float* __restrict__ flag2, const float* __restrict__ symf,
    float* __restrict__ out)
{
    // SoA LDS: broadcast-friendly (inner loop index m is wave-uniform)
    __shared__ float sx1[NPTS], sy1[NPTS], sz1[NPTS];
    __shared__ float sx2[NPTS], sy2[NPTS], sz2[NPTS];
    __shared__ float tx[NPTS], ty[NPTS], tz[NPTS];
    __shared__ float red[8];

    const int bx = blockIdx.x;
    const int b = bx >> 2;          // batch
    const int chunk = bx & 3;       // which 256 of the 1024 point slots
    const int tid = threadIdx.x;

    const float* __restrict__ P1 = p1g + b * NPTS * 3;
    const float* __restrict__ P2 = p2g + b * NPTS * 3;
    const float* __restrict__ T  = tgg + b * NPTS * 3;

    // Stage [1024][3] f32 -> SoA LDS. Coalesced global reads.
    for (int f = tid; f < NPTS * 3; f += 256) {
        int pt = f / 3;
        int c = f - pt * 3;
        float v1 = P1[f], v2 = P2[f], vt = T[f];
        if (c == 0)      { sx1[pt] = v1; sx2[pt] = v2; tx[pt] = vt; }
        else if (c == 1) { sy1[pt] = v1; sy2[pt] = v2; ty[pt] = vt; }
        else             { sz1[pt] = v1; sz2[pt] = v2; tz[pt] = vt; }
    }
    __syncthreads();

    const int i = chunk * 256 + tid;
    const float ax1 = sx1[i], ay1 = sy1[i], az1 = sz1[i];
    const float ax2 = sx2[i], ay2 = sy2[i], az2 = sz2[i];
    const float txi = tx[i],  tyi = ty[i],  tzi = tz[i];

    // min of squared distances; sqrt once at the end (monotone)
    float r1 = 3e38f, c1 = 3e38f, r2 = 3e38f, c2 = 3e38f;

    #pragma unroll 4
    for (int m = 0; m < NPTS; ++m) {
        const float bxm = tx[m],  bym = ty[m],  bzm = tz[m];
        const float q1x = sx1[m], q1y = sy1[m], q1z = sz1[m];
        const float q2x = sx2[m], q2y = sy2[m], q2z = sz2[m];

        float dx = ax1 - bxm, dy = ay1 - bym, dz = az1 - bzm;
        float d = fmaf(dz, dz, fmaf(dy, dy, dx * dx));
        r1 = fminf(r1, d);

        dx = ax2 - bxm; dy = ay2 - bym; dz = az2 - bzm;
        d = fmaf(dz, dz, fmaf(dy, dy, dx * dx));
        r2 = fminf(r2, d);

        dx = q1x - txi; dy = q1y - tyi; dz = q1z - tzi;
        d = fmaf(dz, dz, fmaf(dy, dy, dx * dx));
        c1 = fminf(c1, d);

        dx = q2x - txi; dy = q2y - tyi; dz = q2z - tzi;
        d = fmaf(dz, dz, fmaf(dy, dy, dx * dx));
        c2 = fminf(c2, d);
    }

    const float s1 = 0.5f * (sqrtf(r1) + sqrtf(c1));
    const float s2 = 0.5f * (sqrtf(r2) + sqrtf(c2));

    float dx = ax1 - txi, dy = ay1 - tyi, dz = az1 - tzi;
    const float a1 = sqrtf(fmaf(dz, dz, fmaf(dy, dy, dx * dx)));
    dx = ax2 - txi; dy = ay2 - tyi; dz = az2 - tzi;
    const float a2 = sqrtf(fmaf(dz, dz, fmaf(dy, dy, dx * dx)));

    const float sf = symf[b];
    float l1 = flag1[b] * (sf * s1 + (1.0f - sf) * a1);
    float l2 = flag2[b] * (sf * s2 + (1.0f - sf) * a2);

    // wave (64) reduce, then cross-wave via LDS
    for (int off = 32; off > 0; off >>= 1) {
        l1 += __shfl_down(l1, off);
        l2 += __shfl_down(l2, off);
    }
    const int wave = tid >> 6, lane = tid & 63;
    if (lane == 0) { red[wave * 2] = l1; red[wave * 2 + 1] = l2; }
    __syncthreads();
    if (tid == 0) {
        const float L1 = red[0] + red[2] + red[4] + red[6];
        const float L2 = red[1] + red[3] + red[5] + red[7];
        const float scale = 1.0f / (float)(NPTS * BATCH);
        atomicAdd(&out[0], (L1 + L2) * scale);
        atomicAdd(&out[1], L1 * scale);
        atomicAdd(&out[2], L2 * scale);
    }
}

extern "C" void kernel_launch(void* const* d_in, const int* in_sizes, int n_in,
                              void* d_out, int out_size, void* d_ws, size_t ws_size,
                              hipStream_t stream) {
    const float* p1 = (const float*)d_in[0];
    const float* p2 = (const float*)d_in[1];
    const float* tg = (const float*)d_in[2];
    const float* f1 = (const float*)d_in[3];
    const float* f2 = (const float*)d_in[4];
    const float* sf = (const float*)d_in[5];
    float* out = (float*)d_out;

    zero_out_kernel<<<1, 64, 0, stream>>>(out);
    chamfer_loss_kernel<<<BATCH * 4, 256, 0, stream>>>(p1, p2, tg, f1, f2, sf, out);
}

// Round 2
// 97.432 us; speedup vs baseline: 1.4219x; 1.4219x over previous
//
#include <hip/hip_runtime.h>

// B=64 batches, N=M=1024 3-D points.
// loss = flag * (sym*chamfer + (1-sym)*slotwise_l2), chamfer via bidirectional NN.
// Gram trick: d^2(a,b) = |a|^2 + |b|^2 - 2 a.b ; min over b of (|b|^2 - 2 a.b),
// add |a|^2 once after the min (matches the reference's own formulation).

#define BATCH 64
#define NPTS 1024

__global__ void zero_out_kernel(float* out) {
    if (threadIdx.x < 3) out[threadIdx.x] = 0.0f;
}

__global__ __launch_bounds__(1024, 4) void chamfer_loss_kernel(
    const float* __restrict__ p1g, const float* __restrict__ p2g,
    const float* __restrict__ tgg, const float* __restrict__ flag1,
    const float* __restrict__ flag2, const float* __restrict__ symf,
    float* __restrict__ out)
{
    // AoS float4 (x, y, z, |p|^2): inner-loop reads are wave-uniform broadcast b128
    __shared__ float4 sp1[NPTS];
    __shared__ float4 sp2[NPTS];
    __shared__ float4 st [NPTS];
    __shared__ float4 partA[8][128];   // per (m-group, i-slot): rr1, rr2, cc1, cc2
    __shared__ float4 partB[8][128];
    __shared__ float red[32];

    const int bx = blockIdx.x;
    const int b = bx >> 2;          // batch
    const int chunk = bx & 3;       // which 256 of the 1024 point slots
    const int tid = threadIdx.x;

    const float* __restrict__ P1 = p1g + b * NPTS * 3;
    const float* __restrict__ P2 = p2g + b * NPTS * 3;
    const float* __restrict__ T  = tgg + b * NPTS * 3;

    // Stage all 3 clouds (one point per thread), computing |p|^2 on the fly.
    {
        float x = P1[3*tid+0], y = P1[3*tid+1], z = P1[3*tid+2];
        sp1[tid] = make_float4(x, y, z, fmaf(z, z, fmaf(y, y, x*x)));
        x = P2[3*tid+0]; y = P2[3*tid+1]; z = P2[3*tid+2];
        sp2[tid] = make_float4(x, y, z, fmaf(z, z, fmaf(y, y, x*x)));
        x = T[3*tid+0]; y = T[3*tid+1]; z = T[3*tid+2];
        st[tid]  = make_float4(x, y, z, fmaf(z, z, fmaf(y, y, x*x)));
    }
    __syncthreads();

    const int t  = tid & 127;       // i-slot (owns points ia, ib)
    const int w  = tid >> 7;        // m-group: m in [128w, 128w+128)
    const int ia = chunk * 256 + t;
    const int ib = ia + 128;

    // -2x constants for the fma-form; A/T float4s are re-read from LDS later
    float a1ax, a1ay, a1az, a1bx, a1by, a1bz;
    float a2ax, a2ay, a2az, a2bx, a2by, a2bz;
    float tax, tay, taz, tbx, tby, tbz;
    {
        float4 v;
        v = sp1[ia]; a1ax = -2.f*v.x; a1ay = -2.f*v.y; a1az = -2.f*v.z;
        v = sp1[ib]; a1bx = -2.f*v.x; a1by = -2.f*v.y; a1bz = -2.f*v.z;
        v = sp2[ia]; a2ax = -2.f*v.x; a2ay = -2.f*v.y; a2az = -2.f*v.z;
        v = sp2[ib]; a2bx = -2.f*v.x; a2by = -2.f*v.y; a2bz = -2.f*v.z;
        v = st[ia];  tax  = -2.f*v.x; tay  = -2.f*v.y; taz  = -2.f*v.z;
        v = st[ib];  tbx  = -2.f*v.x; tby  = -2.f*v.y; tbz  = -2.f*v.z;
    }

    float rr1a = 3e38f, rr1b = 3e38f, rr2a = 3e38f, rr2b = 3e38f;
    float cc1a = 3e38f, cc1b = 3e38f, cc2a = 3e38f, cc2b = 3e38f;

    const int m0 = w * 128;
    #pragma unroll 4
    for (int mm = 0; mm < 128; ++mm) {
        const float4 Bt = st [m0 + mm];
        const float4 Q1 = sp1[m0 + mm];
        const float4 Q2 = sp2[m0 + mm];
        // rows: min_m (h_t[m] - 2 a . t[m])  for a = p1[ia], p1[ib], p2[ia], p2[ib]
        rr1a = fminf(rr1a, fmaf(a1ax, Bt.x, fmaf(a1ay, Bt.y, fmaf(a1az, Bt.z, Bt.w))));
        rr1b = fminf(rr1b, fmaf(a1bx, Bt.x, fmaf(a1by, Bt.y, fmaf(a1bz, Bt.z, Bt.w))));
        rr2a = fminf(rr2a, fmaf(a2ax, Bt.x, fmaf(a2ay, Bt.y, fmaf(a2az, Bt.z, Bt.w))));
        rr2b = fminf(rr2b, fmaf(a2bx, Bt.x, fmaf(a2by, Bt.y, fmaf(a2bz, Bt.z, Bt.w))));
        // cols: min_n (h_p[n] - 2 t_i . p[n])  for t_i = t[ia], t[ib]
        cc1a = fminf(cc1a, fmaf(tax, Q1.x, fmaf(tay, Q1.y, fmaf(taz, Q1.z, Q1.w))));
        cc1b = fminf(cc1b, fmaf(tbx, Q1.x, fmaf(tby, Q1.y, fmaf(tbz, Q1.z, Q1.w))));
        cc2a = fminf(cc2a, fmaf(tax, Q2.x, fmaf(tay, Q2.y, fmaf(taz, Q2.z, Q2.w))));
        cc2b = fminf(cc2b, fmaf(tbx, Q2.x, fmaf(tby, Q2.y, fmaf(tbz, Q2.z, Q2.w))));
    }
    partA[w][t] = make_float4(rr1a, rr2a, cc1a, cc2a);
    partB[w][t] = make_float4(rr1b, rr2b, cc1b, cc2b);
    __syncthreads();

    float l1 = 0.f, l2 = 0.f;
    if (w == 0) {
        float4 mA = partA[0][t], mB = partB[0][t];
        #pragma unroll
        for (int k = 1; k < 8; ++k) {
            float4 qa = partA[k][t], qb = partB[k][t];
            mA.x = fminf(mA.x, qa.x); mA.y = fminf(mA.y, qa.y);
            mA.z = fminf(mA.z, qa.z); mA.w = fminf(mA.w, qa.w);
            mB.x = fminf(mB.x, qb.x); mB.y = fminf(mB.y, qb.y);
            mB.z = fminf(mB.z, qb.z); mB.w = fminf(mB.w, qb.w);
        }
        const float sf = symf[b];
        const float4 A1a = sp1[ia], A1b = sp1[ib];
        const float4 A2a = sp2[ia], A2b = sp2[ib];
        const float4 Taa = st [ia], Tbb = st [ib];

        // point ia
        float s1 = 0.5f * (sqrtf(fmaxf(A1a.w + mA.x, 0.f)) + sqrtf(fmaxf(Taa.w + mA.z, 0.f)));
        float s2 = 0.5f * (sqrtf(fmaxf(A2a.w + mA.y, 0.f)) + sqrtf(fmaxf(Taa.w + mA.w, 0.f)));
        float dx = A1a.x - Taa.x, dy = A1a.y - Taa.y, dz = A1a.z - Taa.z;
        float e1 = sqrtf(fmaf(dz, dz, fmaf(dy, dy, dx*dx)));
        dx = A2a.x - Taa.x; dy = A2a.y - Taa.y; dz = A2a.z - Taa.z;
        float e2 = sqrtf(fmaf(dz, dz, fmaf(dy, dy, dx*dx)));
        l1 = sf * s1 + (1.f - sf) * e1;
        l2 = sf * s2 + (1.f - sf) * e2;

        // point ib
        s1 = 0.5f * (sqrtf(fmaxf(A1b.w + mB.x, 0.f)) + sqrtf(fmaxf(Tbb.w + mB.z, 0.f)));
        s2 = 0.5f * (sqrtf(fmaxf(A2b.w + mB.y, 0.f)) + sqrtf(fmaxf(Tbb.w + mB.w, 0.f)));
        dx = A1b.x - Tbb.x; dy = A1b.y - Tbb.y; dz = A1b.z - Tbb.z;
        e1 = sqrtf(fmaf(dz, dz, fmaf(dy, dy, dx*dx)));
        dx = A2b.x - Tbb.x; dy = A2b.y - Tbb.y; dz = A2b.z - Tbb.z;
        e2 = sqrtf(fmaf(dz, dz, fmaf(dy, dy, dx*dx)));
        l1 += sf * s1 + (1.f - sf) * e1;
        l2 += sf * s2 + (1.f - sf) * e2;

        l1 *= flag1[b];
        l2 *= flag2[b];
    }

    // block reduce (waves with w!=0 contribute zeros)
    for (int off = 32; off > 0; off >>= 1) {
        l1 += __shfl_down(l1, off);
        l2 += __shfl_down(l2, off);
    }
    const int wave = tid >> 6, lane = tid & 63;
    if (lane == 0) { red[wave*2] = l1; red[wave*2 + 1] = l2; }
    __syncthreads();
    if (tid == 0) {
        float L1 = 0.f, L2 = 0.f;
        #pragma unroll
        for (int k = 0; k < 16; ++k) { L1 += red[k*2]; L2 += red[k*2 + 1]; }
        const float scale = 1.0f / (float)(NPTS * BATCH);
        atomicAdd(&out[0], (L1 + L2) * scale);
        atomicAdd(&out[1], L1 * scale);
        atomicAdd(&out[2], L2 * scale);
    }
}

extern "C" void kernel_launch(void* const* d_in, const int* in_sizes, int n_in,
                              void* d_out, int out_size, void* d_ws, size_t ws_size,
                              hipStream_t stream) {
    const float* p1 = (const float*)d_in[0];
    const float* p2 = (const float*)d_in[1];
    const float* tg = (const float*)d_in[2];
    const float* f1 = (const float*)d_in[3];
    const float* f2 = (const float*)d_in[4];
    const float* sf = (const float*)d_in[5];
    float* out = (float*)d_out;

    zero_out_kernel<<<1, 64, 0, stream>>>(out);
    chamfer_loss_kernel<<<BATCH * 4, 1024, 0, stream>>>(p1, p2, tg, f1, f2, sf, out);
}

// Round 3
// 95.322 us; speedup vs baseline: 1.4534x; 1.0221x over previous
//
#include <hip/hip_runtime.h>

// B=64 batches, N=M=1024 3-D points.
// loss = flag * (sym*chamfer + (1-sym)*slotwise_l2), chamfer = bidirectional NN.
// Gram residuals (min-compatible):
//   row dir (fixed pred point a): min_m (|t_m|^2 - 2 a.t_m)      [+|a|^2 after]
//   col dir (fixed target t_i):   min_n (|p_n|^2 - 2 t_i.p_n)    [+|t_i|^2 after]
// Each eval = 3 fma from the .w seed; two m's per min -> v_min3_f32 fusion.

#define BATCH 64
#define NPTS 1024

__global__ void zero_out_kernel(float* out) {
    if (threadIdx.x < 3) out[threadIdx.x] = 0.0f;
}

__global__ __launch_bounds__(1024) void chamfer_loss_kernel(
    const float* __restrict__ p1g, const float* __restrict__ p2g,
    const float* __restrict__ tgg, const float* __restrict__ flag1,
    const float* __restrict__ flag2, const float* __restrict__ symf,
    float* __restrict__ out)
{
    // AoS float4 (x, y, z, |p|^2): inner-loop reads are wave-uniform broadcasts
    __shared__ float4 sp1[NPTS];
    __shared__ float4 sp2[NPTS];
    __shared__ float4 st [NPTS];
    __shared__ float4 part[16][64][4];   // [m-group][slot][r1,r2,c1,c2] x 4 points

    const int bx = blockIdx.x;
    const int b = bx >> 2;          // batch
    const int chunk = bx & 3;       // which 256 of the 1024 point slots
    const int tid = threadIdx.x;

    const float* __restrict__ P1 = p1g + b * NPTS * 3;
    const float* __restrict__ P2 = p2g + b * NPTS * 3;
    const float* __restrict__ T  = tgg + b * NPTS * 3;

    // Stage all 3 clouds (one point per thread), |p|^2 in .w
    {
        float x = P1[3*tid+0], y = P1[3*tid+1], z = P1[3*tid+2];
        sp1[tid] = make_float4(x, y, z, fmaf(z, z, fmaf(y, y, x*x)));
        x = P2[3*tid+0]; y = P2[3*tid+1]; z = P2[3*tid+2];
        sp2[tid] = make_float4(x, y, z, fmaf(z, z, fmaf(y, y, x*x)));
        x = T[3*tid+0]; y = T[3*tid+1]; z = T[3*tid+2];
        st[tid]  = make_float4(x, y, z, fmaf(z, z, fmaf(y, y, x*x)));
    }
    __syncthreads();

    const int slot = tid & 63;      // lane == slot; wave == m-group
    const int mg   = tid >> 6;
    const int i0   = chunk * 256 + slot * 4;   // this thread's 4 point indices

    // -2x constants for the fma-form evals
    float r1cx[4], r1cy[4], r1cz[4];
    float r2cx[4], r2cy[4], r2cz[4];
    float tcx[4],  tcy[4],  tcz[4];
    #pragma unroll
    for (int k = 0; k < 4; ++k) {
        float4 v = sp1[i0 + k]; r1cx[k] = -2.f*v.x; r1cy[k] = -2.f*v.y; r1cz[k] = -2.f*v.z;
        v = sp2[i0 + k];        r2cx[k] = -2.f*v.x; r2cy[k] = -2.f*v.y; r2cz[k] = -2.f*v.z;
        v = st [i0 + k];        tcx[k]  = -2.f*v.x; tcy[k]  = -2.f*v.y; tcz[k]  = -2.f*v.z;
    }

    float r1[4], r2[4], c1[4], c2[4];
    #pragma unroll
    for (int k = 0; k < 4; ++k) { r1[k] = 3e38f; r2[k] = 3e38f; c1[k] = 3e38f; c2[k] = 3e38f; }

    const int m0 = mg * 64;
    #pragma unroll 1
    for (int mi = 0; mi < 64; mi += 2) {
        const float4 B0  = st [m0 + mi], B1  = st [m0 + mi + 1];
        const float4 Q10 = sp1[m0 + mi], Q11 = sp1[m0 + mi + 1];
        const float4 Q20 = sp2[m0 + mi], Q21 = sp2[m0 + mi + 1];
        #pragma unroll
        for (int k = 0; k < 4; ++k) {
            float d0, d1;
            d0 = fmaf(r1cx[k], B0.x, fmaf(r1cy[k], B0.y, fmaf(r1cz[k], B0.z, B0.w)));
            d1 = fmaf(r1cx[k], B1.x, fmaf(r1cy[k], B1.y, fmaf(r1cz[k], B1.z, B1.w)));
            r1[k] = fminf(r1[k], fminf(d0, d1));
            d0 = fmaf(r2cx[k], B0.x, fmaf(r2cy[k], B0.y, fmaf(r2cz[k], B0.z, B0.w)));
            d1 = fmaf(r2cx[k], B1.x, fmaf(r2cy[k], B1.y, fmaf(r2cz[k], B1.z, B1.w)));
            r2[k] = fminf(r2[k], fminf(d0, d1));
            d0 = fmaf(tcx[k], Q10.x, fmaf(tcy[k], Q10.y, fmaf(tcz[k], Q10.z, Q10.w)));
            d1 = fmaf(tcx[k], Q11.x, fmaf(tcy[k], Q11.y, fmaf(tcz[k], Q11.z, Q11.w)));
            c1[k] = fminf(c1[k], fminf(d0, d1));
            d0 = fmaf(tcx[k], Q20.x, fmaf(tcy[k], Q20.y, fmaf(tcz[k], Q20.z, Q20.w)));
            d1 = fmaf(tcx[k], Q21.x, fmaf(tcy[k], Q21.y, fmaf(tcz[k], Q21.z, Q21.w)));
            c2[k] = fminf(c2[k], fminf(d0, d1));
        }
    }

    part[mg][slot][0] = make_float4(r1[0], r1[1], r1[2], r1[3]);
    part[mg][slot][1] = make_float4(r2[0], r2[1], r2[2], r2[3]);
    part[mg][slot][2] = make_float4(c1[0], c1[1], c1[2], c1[3]);
    part[mg][slot][3] = make_float4(c2[0], c2[1], c2[2], c2[3]);
    __syncthreads();

    // cross-m-group min: 256 threads, each reduces one (slot, acc-type) float4
    if (tid < 256) {
        const int s = tid >> 2, q = tid & 3;
        float4 m = part[0][s][q];
        #pragma unroll
        for (int g = 1; g < 16; ++g) {
            float4 v = part[g][s][q];
            m.x = fminf(m.x, v.x); m.y = fminf(m.y, v.y);
            m.z = fminf(m.z, v.z); m.w = fminf(m.w, v.w);
        }
        part[0][s][q] = m;
    }
    __syncthreads();

    // finalize: wave 0, one slot per lane (4 points each)
    if (tid < 64) {
        const int s = tid;
        float4 F0 = part[0][s][0];   // row mins, cloud 1
        float4 F1 = part[0][s][1];   // row mins, cloud 2
        float4 F2 = part[0][s][2];   // col mins, cloud 1
        float4 F3 = part[0][s][3];   // col mins, cloud 2
        const float* f0 = &F0.x; const float* f1 = &F1.x;
        const float* f2 = &F2.x; const float* f3 = &F3.x;

        const float sf = symf[b];
        float l1 = 0.f, l2 = 0.f;
        #pragma unroll
        for (int k = 0; k < 4; ++k) {
            const int i = chunk * 256 + s * 4 + k;
            const float4 A1 = sp1[i], A2 = sp2[i], Tt = st[i];
            const float s1 = 0.5f * (sqrtf(fmaxf(A1.w + f0[k], 0.f)) +
                                     sqrtf(fmaxf(Tt.w + f2[k], 0.f)));
            const float s2 = 0.5f * (sqrtf(fmaxf(A2.w + f1[k], 0.f)) +
                                     sqrtf(fmaxf(Tt.w + f3[k], 0.f)));
            float dx = A1.x - Tt.x, dy = A1.y - Tt.y, dz = A1.z - Tt.z;
            const float e1 = sqrtf(fmaf(dz, dz, fmaf(dy, dy, dx*dx)));
            dx = A2.x - Tt.x; dy = A2.y - Tt.y; dz = A2.z - Tt.z;
            const float e2 = sqrtf(fmaf(dz, dz, fmaf(dy, dy, dx*dx)));
            l1 += sf * s1 + (1.f - sf) * e1;
            l2 += sf * s2 + (1.f - sf) * e2;
        }
        l1 *= flag1[b];
        l2 *= flag2[b];

        // wave-0 reduce
        #pragma unroll
        for (int off = 32; off > 0; off >>= 1) {
            l1 += __shfl_down(l1, off);
            l2 += __shfl_down(l2, off);
        }
        if (tid == 0) {
            const float scale = 1.0f / (float)(NPTS * BATCH);
            atomicAdd(&out[0], (l1 + l2) * scale);
            atomicAdd(&out[1], l1 * scale);
            atomicAdd(&out[2], l2 * scale);
        }
    }
}

extern "C" void kernel_launch(void* const* d_in, const int* in_sizes, int n_in,
                              void* d_out, int out_size, void* d_ws, size_t ws_size,
                              hipStream_t stream) {
    const float* p1 = (const float*)d_in[0];
    const float* p2 = (const float*)d_in[1];
    const float* tg = (const float*)d_in[2];
    const float* f1 = (const float*)d_in[3];
    const float* f2 = (const float*)d_in[4];
    const float* sf = (const float*)d_in[5];
    float* out = (float*)d_out;

    zero_out_kernel<<<1, 64, 0, stream>>>(out);
    chamfer_loss_kernel<<<BATCH * 4, 1024, 0, stream>>>(p1, p2, tg, f1, f2, sf, out);
}